// Round 5
// baseline (4577.863 us; speedup 1.0000x reference)
//
#include <hip/hip_runtime.h>
#include <math.h>
#include <stdint.h>

#define N_NODES 50000
#define N_EDGES 400000
#define N_T 4
#define N_R 8
#define N_H 8
#define DKD 32
#define D 256
#define TM 64
#define PROJ_BLOCKS ((N_NODES + TM - 1) / TM + N_T)   // 786 >= sum of per-type ceils
#define EB 32                                          // edges per att block
#define ATT_BLOCKS (N_EDGES / EB + N_R)                // 12508; launch 12512
#define MSG_NODES 16                                   // nodes per msg block
#define SH 264                                         // S LDS: per-head slice stride (u16), 256+8 pad
#define SROW 2120                                      // S LDS: per-node row stride (u16), 8*264+8

typedef __bf16 v8bf __attribute__((ext_vector_type(8)));
typedef float v4f __attribute__((ext_vector_type(4)));
typedef unsigned short u16;

__device__ __forceinline__ float bf2f(u16 u) {
    return __uint_as_float(((unsigned int)u) << 16);
}
__device__ __forceinline__ u16 f2bf(float f) {
    unsigned int u = __float_as_uint(f);
    u += 0x7fffu + ((u >> 16) & 1u);          // RNE
    return (u16)(u >> 16);
}

// load 32 contiguous bf16 -> 32 floats (4x 16B loads)
__device__ __forceinline__ void load_bf32(const u16* __restrict__ p, float* f) {
    const uint4* p4 = (const uint4*)p;
    #pragma unroll
    for (int j = 0; j < 4; j++) {
        uint4 u = p4[j];
        f[8 * j + 0] = __uint_as_float(u.x << 16);
        f[8 * j + 1] = __uint_as_float(u.x & 0xffff0000u);
        f[8 * j + 2] = __uint_as_float(u.y << 16);
        f[8 * j + 3] = __uint_as_float(u.y & 0xffff0000u);
        f[8 * j + 4] = __uint_as_float(u.z << 16);
        f[8 * j + 5] = __uint_as_float(u.z & 0xffff0000u);
        f[8 * j + 6] = __uint_as_float(u.w << 16);
        f[8 * j + 7] = __uint_as_float(u.w & 0xffff0000u);
    }
}

// ---------------- f32 -> bf16 conversion (weights) ----------------
__global__ __launch_bounds__(256) void k_cvt4(const float4* __restrict__ s,
                                              ushort4* __restrict__ d, int n4) {
    int i = blockIdx.x * 256 + threadIdx.x;
    if (i < n4) {
        float4 v = s[i];
        ushort4 o;
        o.x = f2bf(v.x); o.y = f2bf(v.y); o.z = f2bf(v.z); o.w = f2bf(v.w);
        d[i] = o;
    }
}

// rel_msg [r][h][d][f] f32 -> Mt2 [h][f][r*32+d] bf16 (B-operand layout for K=256 GEMM)
__global__ __launch_bounds__(256) void k_cvt_m2(const float* __restrict__ s,
                                                u16* __restrict__ d) {
    int i = blockIdx.x * 256 + threadIdx.x;
    if (i >= N_R * N_H * DKD * DKD) return;
    int f = i & 31, dd = (i >> 5) & 31, h = (i >> 10) & 7, r = i >> 13;
    d[h * 8192 + f * 256 + r * 32 + dd] = f2bf(s[i]);
}

// ---------------- bucketing by node type ----------------
__global__ void k_hist(const int* __restrict__ nt, int* __restrict__ cnt) {
    int n = blockIdx.x * blockDim.x + threadIdx.x;
    if (n < N_NODES) atomicAdd(&cnt[nt[n]], 1);
}

__global__ void k_scan(const int* __restrict__ cnt, int* __restrict__ off,
                       int* __restrict__ toff) {
    int o = 0, to = 0;
    for (int t = 0; t < N_T; t++) {
        off[t] = o; toff[t] = to;
        o += cnt[t]; to += (cnt[t] + TM - 1) / TM;
    }
    off[N_T] = o; toff[N_T] = to;
}

__global__ void k_scatter(const int* __restrict__ nt, const int* __restrict__ off,
                          int* __restrict__ cur, int* __restrict__ order) {
    int n = blockIdx.x * blockDim.x + threadIdx.x;
    if (n >= N_NODES) return;
    int t = nt[n];
    int pos = off[t] + atomicAdd(&cur[t], 1);
    order[pos] = n;
}

// ---------------- dst-CSR build (packed records) ----------------
__global__ void k_hist2(const int* __restrict__ dst, int* __restrict__ cnt2) {
    int e = blockIdx.x * blockDim.x + threadIdx.x;
    if (e < N_EDGES) atomicAdd(&cnt2[dst[e]], 1);
}

__global__ __launch_bounds__(1024) void k_scan2(const int* __restrict__ cnt2,
                                                int* __restrict__ rowptr) {
    __shared__ int sh[1024];
    __shared__ int carry;
    int tid = threadIdx.x;
    if (tid == 0) carry = 0;
    __syncthreads();
    for (int base = 0; base < N_NODES; base += 1024) {
        int i = base + tid;
        int v = (i < N_NODES) ? cnt2[i] : 0;
        sh[tid] = v;
        __syncthreads();
        #pragma unroll
        for (int ofs = 1; ofs < 1024; ofs <<= 1) {
            int t = (tid >= ofs) ? sh[tid - ofs] : 0;
            __syncthreads();
            sh[tid] += t;
            __syncthreads();
        }
        if (i < N_NODES) rowptr[i] = carry + sh[tid] - v;   // exclusive
        int total = sh[1023];
        __syncthreads();
        if (tid == 0) carry += total;
        __syncthreads();
    }
    if (tid == 0) rowptr[N_NODES] = carry;
}

// pk[pos] = (src | etype<<20, original_e)
__global__ void k_scatter2(const int* __restrict__ dst, const int* __restrict__ src,
                           const int* __restrict__ et, const int* __restrict__ rowptr,
                           int* __restrict__ cur2, int2* __restrict__ pk) {
    int e = blockIdx.x * blockDim.x + threadIdx.x;
    if (e >= N_EDGES) return;
    int d = dst[e];
    int pos = rowptr[d] + atomicAdd(&cur2[d], 1);
    pk[pos] = make_int2(src[e] | (et[e] << 20), e);
}

// ---------------- r-sort for attention ----------------
__global__ void k_hist_r(const int* __restrict__ et, int* __restrict__ rh) {
    int e = blockIdx.x * blockDim.x + threadIdx.x;
    if (e < N_EDGES) atomicAdd(&rh[et[e]], 1);
}

__global__ void k_scan_r(const int* __restrict__ rh, int* __restrict__ ro,
                         int* __restrict__ bo) {
    int o = 0, b = 0;
    for (int r = 0; r < N_R; r++) {
        ro[r] = o; bo[r] = b;
        o += rh[r]; b += (rh[r] + EB - 1) / EB;
    }
    ro[N_R] = o; bo[N_R] = b;
}

__global__ void k_scatter_r(const int* __restrict__ et, const int* __restrict__ ro,
                            int* __restrict__ rc, int* __restrict__ er) {
    int e = blockIdx.x * blockDim.x + threadIdx.x;
    if (e >= N_EDGES) return;
    int r = et[e];
    int pos = ro[r] + atomicAdd(&rc[r], 1);
    er[pos] = e;
}

// ---------------- fused typed K/Q/V projection (MFMA) ----------------
__global__ __launch_bounds__(256) void k_proj(
    const float* __restrict__ x, const int* __restrict__ order,
    const int* __restrict__ off, const int* __restrict__ toff,
    const u16* __restrict__ Wkb, const float* __restrict__ bk,
    const u16* __restrict__ Wqb, const float* __restrict__ bq,
    const u16* __restrict__ Wvb, const float* __restrict__ bv,
    u16* __restrict__ Kb, u16* __restrict__ Qb, u16* __restrict__ Vb) {
    __shared__ __align__(16) u16 xs[TM][D + 8];
    int b = blockIdx.x;
    int t = -1;
    #pragma unroll
    for (int i = 0; i < N_T; i++)
        if (b >= toff[i] && b < toff[i + 1]) t = i;
    if (t < 0) return;
    int nodeBase = off[t] + (b - toff[t]) * TM;
    int count = min(TM, off[t + 1] - nodeBase);
    int tid = threadIdx.x;

    for (int j = tid; j < TM * (D / 4); j += 256) {
        int row = j >> 6, ch = j & 63;
        float4 v = {0.f, 0.f, 0.f, 0.f};
        if (row < count) {
            int g = order[nodeBase + row];
            v = *(const float4*)(x + (size_t)g * D + ch * 4);
        }
        ushort4 o;
        o.x = f2bf(v.x); o.y = f2bf(v.y); o.z = f2bf(v.z); o.w = f2bf(v.w);
        *(ushort4*)&xs[row][ch * 4] = o;
    }
    __syncthreads();

    int lane = tid & 63, wave = tid >> 6;
    int m = lane & 15, quad = lane >> 4;
    v8bf a[8];
    #pragma unroll
    for (int ks = 0; ks < 8; ks++)
        a[ks] = *(const v8bf*)&xs[wave * 16 + m][ks * 32 + quad * 8];

    int grow[4]; bool vrow[4];
    #pragma unroll
    for (int r = 0; r < 4; r++) {
        int rowi = wave * 16 + quad * 4 + r;
        vrow[r] = (rowi < count);
        grow[r] = vrow[r] ? order[nodeBase + rowi] : 0;
    }

    const u16* Ws[3] = {Wkb + (size_t)t * D * D, Wqb + (size_t)t * D * D, Wvb + (size_t)t * D * D};
    const float* Bs[3] = {bk + t * D, bq + t * D, bv + t * D};
    u16* Os[3] = {Kb, Qb, Vb};

    for (int p = 0; p < 3; p++) {
        const u16* W = Ws[p];
        for (int dt = 0; dt < 16; dt++) {
            int dcol = dt * 16 + m;
            v4f acc = {0.f, 0.f, 0.f, 0.f};
            #pragma unroll
            for (int ks = 0; ks < 8; ks++) {
                v8bf bf = *(const v8bf*)(W + (size_t)dcol * D + ks * 32 + quad * 8);
                acc = __builtin_amdgcn_mfma_f32_16x16x32_bf16(a[ks], bf, acc, 0, 0, 0);
            }
            float bias = Bs[p][dcol];
            #pragma unroll
            for (int r = 0; r < 4; r++) {
                if (vrow[r])
                    Os[p][(size_t)grow[r] * D + dcol] = f2bf(acc[r] + bias);
            }
        }
    }
}

// ---------------- edge attention v2: r-grouped blocks, A staged f32 in LDS ----------------
__global__ __launch_bounds__(256) void k_edge_att2(
    const u16* __restrict__ Kb, const u16* __restrict__ Qb,
    const int* __restrict__ src, const int* __restrict__ dst,
    const float* __restrict__ rel_att, const float* __restrict__ pri,
    const int* __restrict__ er, const int* __restrict__ ro, const int* __restrict__ bo,
    float* __restrict__ EX, float* __restrict__ DEN) {
    __shared__ __align__(16) float A32[N_H * 1028 + 4];   // stride 1028: bank-spread per h
    int b = blockIdx.x;
    int r = -1;
    #pragma unroll
    for (int i = 0; i < N_R; i++)
        if (b >= bo[i] && b < bo[i + 1]) r = i;
    if (r < 0) return;

    {   // stage this r's 8 head matrices as f32
        const float4* sA = (const float4*)(rel_att + (size_t)r * N_H * DKD * DKD);
        for (int i = threadIdx.x; i < 2048; i += 256) {
            float4 v = sA[i];
            int h = i >> 8, rem = i & 255;
            int d0 = rem >> 3, fq = rem & 7;
            *(float4*)&A32[h * 1028 + d0 * 32 + fq * 4] = v;
        }
    }
    __syncthreads();

    int base = ro[r] + (b - bo[r]) * EB;
    int cnt = min(EB, ro[r + 1] - base);
    int el = threadIdx.x >> 3, h = threadIdx.x & 7;
    if (el >= cnt) return;
    int e = er[base + el];
    int s = src[e], d = dst[e];

    float qv[DKD], kv[DKD];
    load_bf32(Qb + (size_t)d * D + h * DKD, qv);
    load_bf32(Kb + (size_t)s * D + h * DKD, kv);

    const float* Ah = &A32[h * 1028];
    float att = 0.f;
    #pragma unroll 4
    for (int d0 = 0; d0 < DKD; d0++) {
        const float4* Ar = (const float4*)(Ah + d0 * 32);
        float tmp = 0.f;
        #pragma unroll
        for (int j = 0; j < 8; j++) {
            float4 a4 = Ar[j];
            tmp += a4.x * qv[4 * j] + a4.y * qv[4 * j + 1]
                 + a4.z * qv[4 * j + 2] + a4.w * qv[4 * j + 3];
        }
        att += kv[d0] * tmp;
    }
    att *= pri[r * N_H + h] * 0.17677669529663687f;   // 1/sqrt(32)
    float ex = __expf(att);
    EX[(size_t)e * N_H + h] = ex;
    unsafeAtomicAdd(&DEN[((size_t)d * N_R + r) * N_H + h], ex);
}

// ---------------- fused message: S-accumulate (regs) -> LDS -> in-block GEMM ----------------
// Block = 16 nodes; wave w owns nodes w*4..w*4+3 for gather, heads 2w,2w+1 for GEMM.
__global__ __launch_bounds__(256) void k_msg_fused(
    const u16* __restrict__ Vb, const int2* __restrict__ pk,
    const int* __restrict__ rowptr, const u16* __restrict__ Mt2,
    const float* __restrict__ EX, const float* __restrict__ DEN,
    u16* __restrict__ TBF) {
    __shared__ __align__(16) u16 S[MSG_NODES][SROW];
    int wave = threadIdx.x >> 6, lane = threadIdx.x & 63;
    int nb = blockIdx.x * MSG_NODES;
    int hg = lane >> 3, dq = lane & 7;    // gather role: (head, d-quad)
    int rr = lane >> 3, hh = lane & 7;    // invd role: lane = r*8+h

    for (int j = 0; j < 4; j++) {
        int n = nb + wave * 4 + j;
        float den = DEN[((size_t)n * N_R + rr) * N_H + hh];
        float invd = (den > 0.f) ? (1.f / den) : 0.f;
        unsigned long long bal = __ballot(den > 0.f);
        int P = __popcll(bal & 0x0101010101010101ULL);
        float invp = (P > 0) ? (1.f / (float)P) : 1.f;

        float acc[N_R][4];
        #pragma unroll
        for (int r = 0; r < N_R; r++)
            { acc[r][0] = 0.f; acc[r][1] = 0.f; acc[r][2] = 0.f; acc[r][3] = 0.f; }

        int st = rowptr[n], en = rowptr[n + 1];
        int2 mn;
        if (st < en) mn = pk[st];
        for (int ei = st; ei < en; ei++) {
            int2 mc = mn;
            if (ei + 1 < en) mn = pk[ei + 1];
            int s = mc.x & 0xFFFFF;
            int r = mc.x >> 20;
            float exv = EX[(size_t)mc.y * N_H + hg];
            uint2 vv = *(const uint2*)(Vb + (size_t)s * D + hg * DKD + dq * 4);
            float w = exv * __shfl(invd, r * 8 + hg, 64);
            float f0 = __uint_as_float(vv.x << 16);
            float f1 = __uint_as_float(vv.x & 0xffff0000u);
            float f2_ = __uint_as_float(vv.y << 16);
            float f3 = __uint_as_float(vv.y & 0xffff0000u);
            switch (r) {
            #define CASE(R) case R: acc[R][0] += w * f0; acc[R][1] += w * f1; \
                                    acc[R][2] += w * f2_; acc[R][3] += w * f3; break;
            CASE(0) CASE(1) CASE(2) CASE(3) CASE(4) CASE(5) CASE(6) CASE(7)
            #undef CASE
            }
        }
        // write node's S slice (x invp), bf16
        int row = wave * 4 + j;
        #pragma unroll
        for (int r = 0; r < N_R; r++) {
            ushort4 o;
            o.x = f2bf(acc[r][0] * invp); o.y = f2bf(acc[r][1] * invp);
            o.z = f2bf(acc[r][2] * invp); o.w = f2bf(acc[r][3] * invp);
            *(ushort4*)&S[row][hg * SH + r * 32 + dq * 4] = o;
        }
    }
    __syncthreads();

    // GEMM: T[16 nodes, h*32+f] = S[16, K=256] x Mt2[h][f][K]
    int m = lane & 15, quad = lane >> 4;
    for (int hi = 0; hi < 2; hi++) {
        int h = wave * 2 + hi;
        const u16* Mh = Mt2 + (size_t)h * 8192;
        #pragma unroll
        for (int ft = 0; ft < 2; ft++) {
            int fcol = ft * 16 + m;
            const u16* Bp = Mh + (size_t)fcol * 256;
            v4f acc = {0.f, 0.f, 0.f, 0.f};
            #pragma unroll
            for (int ks = 0; ks < 8; ks++) {
                v8bf a = *(const v8bf*)&S[m][h * SH + ks * 32 + quad * 8];
                v8bf bb = *(const v8bf*)(Bp + ks * 32 + quad * 8);
                acc = __builtin_amdgcn_mfma_f32_16x16x32_bf16(a, bb, acc, 0, 0, 0);
            }
            #pragma unroll
            for (int i = 0; i < 4; i++) {
                int node = nb + quad * 4 + i;
                TBF[(size_t)node * D + h * DKD + fcol] = f2bf(acc[i]);
            }
        }
    }
}

// ---------------- typed output linear + sigmoid-skip blend (MFMA) ----------------
__global__ __launch_bounds__(256) void k_out(
    const u16* __restrict__ TBF, const float* __restrict__ x,
    const int* __restrict__ order, const int* __restrict__ off, const int* __restrict__ toff,
    const u16* __restrict__ Wab, const float* __restrict__ ba,
    const float* __restrict__ skip, float* __restrict__ out) {
    __shared__ __align__(16) u16 xs[TM][D + 8];
    int b = blockIdx.x;
    int t = -1;
    #pragma unroll
    for (int i = 0; i < N_T; i++)
        if (b >= toff[i] && b < toff[i + 1]) t = i;
    if (t < 0) return;
    int nodeBase = off[t] + (b - toff[t]) * TM;
    int count = min(TM, off[t + 1] - nodeBase);
    int tid = threadIdx.x;

    for (int j = tid; j < TM * 32; j += 256) {
        int row = j >> 5, ch = j & 31;
        ushort4 z = {0, 0, 0, 0};
        if (row < count) {
            int g = order[nodeBase + row];
            const ushort4* p = (const ushort4*)(TBF + (size_t)g * D + ch * 8);
            *(ushort4*)&xs[row][ch * 8] = p[0];
            *(ushort4*)&xs[row][ch * 8 + 4] = p[1];
        } else {
            *(ushort4*)&xs[row][ch * 8] = z;
            *(ushort4*)&xs[row][ch * 8 + 4] = z;
        }
    }
    __syncthreads();

    int lane = tid & 63, wave = tid >> 6;
    int m = lane & 15, quad = lane >> 4;
    v8bf a[8];
    #pragma unroll
    for (int ks = 0; ks < 8; ks++)
        a[ks] = *(const v8bf*)&xs[wave * 16 + m][ks * 32 + quad * 8];

    int grow[4]; bool vrow[4];
    #pragma unroll
    for (int r = 0; r < 4; r++) {
        int rowi = wave * 16 + quad * 4 + r;
        vrow[r] = (rowi < count);
        grow[r] = vrow[r] ? order[nodeBase + rowi] : 0;
    }

    float sv = skip[t];
    float alpha = 1.f / (1.f + __expf(-sv));
    float beta = 1.f - alpha;
    const u16* W = Wab + (size_t)t * D * D;

    for (int dt = 0; dt < 16; dt++) {
        int dcol = dt * 16 + m;
        v4f acc = {0.f, 0.f, 0.f, 0.f};
        #pragma unroll
        for (int ks = 0; ks < 8; ks++) {
            v8bf bf = *(const v8bf*)(W + (size_t)dcol * D + ks * 32 + quad * 8);
            acc = __builtin_amdgcn_mfma_f32_16x16x32_bf16(a[ks], bf, acc, 0, 0, 0);
        }
        float bias = ba[t * D + dcol];
        #pragma unroll
        for (int r = 0; r < 4; r++) {
            if (vrow[r]) {
                size_t o = (size_t)grow[r] * D + dcol;
                out[o] = alpha * (acc[r] + bias) + beta * x[o];
            }
        }
    }
}

// ---------------- launch ----------------
extern "C" void kernel_launch(void* const* d_in, const int* in_sizes, int n_in,
                              void* d_out, int out_size, void* d_ws, size_t ws_size,
                              hipStream_t stream) {
    const float* x       = (const float*)d_in[0];
    const int* node_type = (const int*)d_in[1];
    const int* src       = (const int*)d_in[2];
    const int* dst       = (const int*)d_in[3];
    const int* etype     = (const int*)d_in[4];
    const float* Wk = (const float*)d_in[5];
    const float* bk = (const float*)d_in[6];
    const float* Wq = (const float*)d_in[7];
    const float* bq = (const float*)d_in[8];
    const float* Wv = (const float*)d_in[9];
    const float* bv = (const float*)d_in[10];
    const float* Wa = (const float*)d_in[11];
    const float* ba = (const float*)d_in[12];
    const float* rel_pri = (const float*)d_in[13];
    const float* rel_att = (const float*)d_in[14];
    const float* rel_msg = (const float*)d_in[15];
    const float* skip    = (const float*)d_in[16];
    float* out = (float*)d_out;
    char* ws = (char*)d_ws;

    // ws (~80 MB): Kb | Qb | Vb (bf16), Wkb..Wab (bf16), Mt2, order, counters.
    // TBF aliases Kb (dead after k_edge_att2; k_msg_fused reads Vb only).
    const size_t SZH = (size_t)N_NODES * D * 2;          // 25.6 MB
    const size_t WSZ = (size_t)N_T * D * D;              // 262144 elems
    const size_t RSZ = (size_t)N_R * N_H * DKD * DKD;    // 65536 elems
    u16* Kb  = (u16*)(ws);
    u16* Qb  = (u16*)(ws + SZH);
    u16* Vb  = (u16*)(ws + 2 * SZH);
    u16* TBF = (u16*)(ws);                      // aliases Kb
    u16* Wkb = (u16*)(ws + 3 * SZH);
    u16* Wqb = Wkb + WSZ;
    u16* Wvb = Wqb + WSZ;
    u16* Wab = Wvb + WSZ;
    u16* Mt2 = Wab + WSZ;                       // [h][f][r*32+d] bf16, 128KB
    int* order = (int*)(Mt2 + RSZ);
    int* small = order + N_NODES;
    int* cnt  = small;        // 4
    int* cur  = small + 4;    // 4
    int* offp = small + 8;    // 5
    int* toffp= small + 13;   // 5

    // d_out scratch (~31 MB of 51.2; all dead before k_out rewrites):
    char* ob = (char*)d_out;
    float* EX  = (float*)ob;                                   // 3.2M f32
    float* DEN = EX + (size_t)N_EDGES * N_H;                   // 3.2M f32
    int* rowptr = (int*)(DEN + (size_t)N_NODES * N_R * N_H / 8 * 0 + (size_t)N_NODES * N_R * N_H); // after DEN
    int* cnt2   = rowptr + N_NODES + 4;            // 50000
    int* cur2   = cnt2 + N_NODES;                  // 50000
    int2* pk    = (int2*)(cur2 + N_NODES);         // 400000 int2 (8B-aligned: offset div by 8)
    int* er     = (int*)(pk + N_EDGES);            // 400000
    int* rh     = er + N_EDGES;                    // 8
    int* rc     = rh + N_R;                        // 8
    int* ro     = rc + N_R;                        // 9
    int* bo     = ro + (N_R + 1);                  // 9

    hipMemsetAsync(small, 0, 8 * sizeof(int), stream);
    hipMemsetAsync(DEN, 0, (size_t)N_NODES * N_R * N_H * 4, stream);
    hipMemsetAsync(cnt2, 0, 2 * N_NODES * sizeof(int), stream);
    hipMemsetAsync(rh, 0, 2 * N_R * sizeof(int), stream);

    // weight conversions
    k_cvt4<<<(WSZ / 4 + 255) / 256, 256, 0, stream>>>((const float4*)Wk, (ushort4*)Wkb, WSZ / 4);
    k_cvt4<<<(WSZ / 4 + 255) / 256, 256, 0, stream>>>((const float4*)Wq, (ushort4*)Wqb, WSZ / 4);
    k_cvt4<<<(WSZ / 4 + 255) / 256, 256, 0, stream>>>((const float4*)Wv, (ushort4*)Wvb, WSZ / 4);
    k_cvt4<<<(WSZ / 4 + 255) / 256, 256, 0, stream>>>((const float4*)Wa, (ushort4*)Wab, WSZ / 4);
    k_cvt_m2<<<(RSZ + 255) / 256, 256, 0, stream>>>(rel_msg, Mt2);

    // node-type buckets
    k_hist<<<(N_NODES + 255) / 256, 256, 0, stream>>>(node_type, cnt);
    k_scan<<<1, 1, 0, stream>>>(cnt, offp, toffp);
    k_scatter<<<(N_NODES + 255) / 256, 256, 0, stream>>>(node_type, offp, cur, order);

    // dst CSR with packed records
    k_hist2<<<(N_EDGES + 255) / 256, 256, 0, stream>>>(dst, cnt2);
    k_scan2<<<1, 1024, 0, stream>>>(cnt2, rowptr);
    k_scatter2<<<(N_EDGES + 255) / 256, 256, 0, stream>>>(dst, src, etype, rowptr, cur2, pk);

    // r-sorted edge list for attention
    k_hist_r<<<(N_EDGES + 255) / 256, 256, 0, stream>>>(etype, rh);
    k_scan_r<<<1, 1, 0, stream>>>(rh, ro, bo);
    k_scatter_r<<<(N_EDGES + 255) / 256, 256, 0, stream>>>(etype, ro, rc, er);

    k_proj<<<PROJ_BLOCKS, 256, 0, stream>>>(x, order, offp, toffp,
                                            Wkb, bk, Wqb, bq, Wvb, bv, Kb, Qb, Vb);

    k_edge_att2<<<ATT_BLOCKS + 4, 256, 0, stream>>>(
        Kb, Qb, src, dst, rel_att, rel_pri, er, ro, bo, EX, DEN);

    k_msg_fused<<<N_NODES / MSG_NODES, 256, 0, stream>>>(
        Vb, pk, rowptr, Mt2, EX, DEN, TBF);

    k_out<<<PROJ_BLOCKS, 256, 0, stream>>>(TBF, x, order, offp, toffp,
                                           Wab, ba, skip, out);
}